// Round 1
// baseline (504.501 us; speedup 1.0000x reference)
//
#include <hip/hip_runtime.h>
#include <hip/hip_bf16.h>

typedef unsigned short u16;
typedef __attribute__((ext_vector_type(8))) short    bf16x8;  // MFMA A/B frag (8 bf16)
typedef __attribute__((ext_vector_type(8))) unsigned short u16x8;
typedef __attribute__((ext_vector_type(4))) float    f32x4;   // MFMA C/D frag

typedef __attribute__((address_space(1))) void gvoid;
typedef __attribute__((address_space(3))) void lvoid;

#define SEQ    1024
#define DMODEL 1024
#define NHEAD  16
#define HDIM   64

#define OUT_OFF_SREL 2097152UL
#define OUT_OFF_QE   35651584UL

#define MFMA16(a, b, c) __builtin_amdgcn_mfma_f32_16x16x32_bf16((a), (b), (c), 0, 0, 0)

__device__ __forceinline__ float b2f(u16 u) {
    union { unsigned int i; float f; } x; x.i = ((unsigned int)u) << 16; return x.f;
}
__device__ __forceinline__ u16 f2b(float f) {
    union { __hip_bfloat16 h; u16 u; } x; x.h = __float2bfloat16(f); return x.u;
}
__device__ __forceinline__ void st_out(void* p, size_t idx, float v, int isf32) {
    if (isf32) ((float*)p)[idx] = v;
    else       ((u16*)p)[idx]   = f2b(v);
}
// async global->LDS, 16B per lane. LDS dest = wave-uniform base + lane*16.
__device__ __forceinline__ void gload_lds16(const u16* g, u16* l) {
    __builtin_amdgcn_global_load_lds((gvoid*)g, (lvoid*)l, 16, 0, 0);
}

// ---------------------------------------------------------------------------
// dtype detect (fp32 vs bf16)
// ---------------------------------------------------------------------------
__global__ __launch_bounds__(256)
void k_detect(const u16* __restrict__ q, unsigned* __restrict__ flag)
{
    __shared__ int cnt;
    if (threadIdx.x == 0) cnt = 0;
    __syncthreads();
    int plaus = 0;
    for (int i = threadIdx.x; i < 4096; i += 256) {
        u16 u = q[2 * i];
        int e = (u >> 7) & 0xFF;
        if (e >= 102 && e <= 130) plaus++;
    }
    atomicAdd(&cnt, plaus);
    __syncthreads();
    if (threadIdx.x == 0) *flag = (cnt < 2048) ? 1u : 0u;
}

// ---------------------------------------------------------------------------
// ALL conversions in one launch (was 3 kernels):
//   blocks [0,6144):    q/k/v convert (2048 blocks each)
//   blocks [6144,7168): 4x 1024x1024 transpose+convert (256 blocks each)
//   blocks [7168,7236): e_r (64 blocks) + 4 biases
// ---------------------------------------------------------------------------
__global__ __launch_bounds__(256)
void k_conv_all(const void* __restrict__ sq, const void* __restrict__ sk, const void* __restrict__ sv,
                const void* __restrict__ w0, const void* __restrict__ w1,
                const void* __restrict__ w2, const void* __restrict__ w3,
                const void* __restrict__ b0, const void* __restrict__ b1,
                const void* __restrict__ b2, const void* __restrict__ b3,
                const void* __restrict__ erp,
                u16* __restrict__ cq, u16* __restrict__ ck, u16* __restrict__ cv,
                u16* __restrict__ d0, u16* __restrict__ d1,
                u16* __restrict__ d2, u16* __restrict__ d3,
                u16* __restrict__ db0, u16* __restrict__ db1,
                u16* __restrict__ db2, u16* __restrict__ db3,
                u16* __restrict__ der, const unsigned* __restrict__ flag)
{
    __shared__ u16 tile[64][65];
    const int t = threadIdx.x;
    const int b = blockIdx.x;
    const int isf32 = (*flag != 0u);

    if (b < 6144) {                      // q/k/v: 2048 blocks per tensor, exact
        const int z = b >> 11;
        const void* src = (z == 0) ? sq : (z == 1) ? sk : sv;
        u16* dst = (z == 0) ? cq : (z == 1) ? ck : cv;
        const int i = (b & 2047) * 256 + t;
        if (isf32) {
            float4 f = ((const float4*)src)[i];
            ushort4 o;
            o.x = f2b(f.x); o.y = f2b(f.y); o.z = f2b(f.z); o.w = f2b(f.w);
            ((ushort4*)dst)[i] = o;
        } else {
            ((ushort4*)dst)[i] = ((const ushort4*)src)[i];
        }
    } else if (b < 7168) {               // weight transpose
        const int bb = b - 6144;
        const int z  = bb >> 8;
        const void* src = (z == 0) ? w0 : (z == 1) ? w1 : (z == 2) ? w2 : w3;
        u16* dst = (z == 0) ? d0 : (z == 1) ? d1 : (z == 2) ? d2 : d3;
        const int n0 = (bb & 15) * 64;
        const int k0 = ((bb >> 4) & 15) * 64;

        #pragma unroll
        for (int i = 0; i < 4; ++i) {
            int idx = i * 256 + t;
            int r  = idx >> 4;
            int cg = (idx & 15) << 2;
            if (isf32) {
                float4 f = *(const float4*)((const float*)src + (size_t)(k0 + r) * 1024 + n0 + cg);
                tile[cg + 0][r] = f2b(f.x); tile[cg + 1][r] = f2b(f.y);
                tile[cg + 2][r] = f2b(f.z); tile[cg + 3][r] = f2b(f.w);
            } else {
                ushort4 u = *(const ushort4*)((const u16*)src + (size_t)(k0 + r) * 1024 + n0 + cg);
                tile[cg + 0][r] = u.x; tile[cg + 1][r] = u.y;
                tile[cg + 2][r] = u.z; tile[cg + 3][r] = u.w;
            }
        }
        __syncthreads();
        #pragma unroll
        for (int i = 0; i < 4; ++i) {
            int idx = i * 256 + t;
            int nl = idx >> 4;
            int kg = (idx & 15) << 2;
            ushort4 o;
            o.x = tile[nl][kg + 0]; o.y = tile[nl][kg + 1];
            o.z = tile[nl][kg + 2]; o.w = tile[nl][kg + 3];
            *(ushort4*)(dst + (size_t)(n0 + nl) * 1024 + k0 + kg) = o;
        }
    } else {                             // e_r + biases
        const int bx = b - 7168;
        const void* src; u16* dst; int i;
        if (bx < 64) { src = erp; dst = der; i = bx * 256 + t; }
        else {
            const int which = bx - 64;
            src = (which == 0) ? b0 : (which == 1) ? b1 : (which == 2) ? b2 : b3;
            dst = (which == 0) ? db0 : (which == 1) ? db1 : (which == 2) ? db2 : db3;
            i = t;
        }
        if (isf32) {
            float4 f = ((const float4*)src)[i];
            ushort4 o;
            o.x = f2b(f.x); o.y = f2b(f.y); o.z = f2b(f.z); o.w = f2b(f.w);
            ((ushort4*)dst)[i] = o;
        } else {
            ((ushort4*)dst)[i] = ((const ushort4*)src)[i];
        }
    }
}

// ---------------------------------------------------------------------------
// MFMA GEMM (m97 structure): global_load_lds width-16 staging, linear LDS.
// C[m][n] = sum_k A[m][k] * Wt[n][k]. 128x128 tile, BK=64.
// ---------------------------------------------------------------------------
__global__ __launch_bounds__(256)
void k_gemm(const u16* __restrict__ Aq, const u16* __restrict__ Ak, const u16* __restrict__ Av,
            const u16* __restrict__ Wtq, const u16* __restrict__ Wtk, const u16* __restrict__ Wtv,
            const u16* __restrict__ Bq, const u16* __restrict__ Bk, const u16* __restrict__ Bv,
            u16* __restrict__ Oq, u16* __restrict__ Ok, u16* __restrict__ Ov,
            void* __restrict__ out_flat, const unsigned* __restrict__ flag, int mode)
{
    __shared__ __align__(16) u16 Xs[128][64];   // linear: global_load_lds dest
    __shared__ __align__(16) u16 Ws[128][64];

    const int z = blockIdx.z;
    const u16* A  = (z == 0) ? Aq : (z == 1) ? Ak : Av;
    const u16* Wt = (z == 0) ? Wtq : (z == 1) ? Wtk : Wtv;
    const u16* Bi = (z == 0) ? Bq : (z == 1) ? Bk : Bv;
    u16* O = (z == 0) ? Oq : (z == 1) ? Ok : Ov;

    const int t    = threadIdx.x;
    const int lane = t & 63;
    const int w    = t >> 6;
    const int q4   = lane >> 4;
    const int l16  = lane & 15;
    const int wy   = w >> 1, wx = w & 1;
    const int m0   = blockIdx.y * 128;
    const int n0   = blockIdx.x * 128;

    f32x4 acc[4][4] = {};

    for (int k0 = 0; k0 < DMODEL; k0 += 64) {
        __syncthreads();
        #pragma unroll
        for (int i = 0; i < 4; ++i) {
            const int idx = i * 256 + t;
            const int row = idx >> 3;
            const int kg  = (idx & 7) << 3;
            const int wb  = i * 256 + (t & 192);            // wave-uniform LDS base (u16 idx /8)
            gload_lds16(A  + (size_t)(m0 + row) * 1024 + k0 + kg, (u16*)Xs + (size_t)wb * 8);
            gload_lds16(Wt + (size_t)(n0 + row) * 1024 + k0 + kg, (u16*)Ws + (size_t)wb * 8);
        }
        __syncthreads();                                    // drains vmcnt (m97 pattern)
        #pragma unroll
        for (int kc = 0; kc < 2; ++kc) {
            bf16x8 af[4], bfr[4];
            #pragma unroll
            for (int mt = 0; mt < 4; ++mt)
                af[mt] = *(const bf16x8*)&Xs[wy * 64 + mt * 16 + l16][kc * 32 + q4 * 8];
            #pragma unroll
            for (int nt = 0; nt < 4; ++nt)
                bfr[nt] = *(const bf16x8*)&Ws[wx * 64 + nt * 16 + l16][kc * 32 + q4 * 8];
            #pragma unroll
            for (int mt = 0; mt < 4; ++mt)
                #pragma unroll
                for (int nt = 0; nt < 4; ++nt)
                    acc[mt][nt] = MFMA16(af[mt], bfr[nt], acc[mt][nt]);
        }
    }

    const int isf32 = (*flag != 0u);
    float bias[4];
    #pragma unroll
    for (int nt = 0; nt < 4; ++nt) bias[nt] = b2f(Bi[n0 + wx * 64 + nt * 16 + l16]);

    #pragma unroll
    for (int mt = 0; mt < 4; ++mt) {
        #pragma unroll
        for (int nt = 0; nt < 4; ++nt) {
            #pragma unroll
            for (int reg = 0; reg < 4; ++reg) {
                const int m = m0 + wy * 64 + mt * 16 + q4 * 4 + reg;
                const int n = n0 + wx * 64 + nt * 16 + l16;
                const float v = acc[mt][nt][reg] + bias[nt];
                if (mode == 0) {
                    const int b = m >> 10, s = m & 1023, h = n >> 6, d = n & 63;
                    O[(((size_t)(b * NHEAD + h)) * SEQ + s) * HDIM + d] = f2b(v);
                } else {
                    st_out(out_flat, (size_t)m * DMODEL + n, v, isf32);
                }
            }
        }
    }
}

// ---------------------------------------------------------------------------
// k_attn (MFMA flash, fused qe/S_rel producer).
// Changes this round:
//  - K and E MFMA B-frags loaded DIRECTLY from global (L2-hot; staging was
//    pure overhead per Common-mistake #7). LDS 79 KB -> 52 KB.
//  - complementary q-tile ordering: blocks [0,256) get qt 15..8, blocks
//    [256,512) get qt 0..7, so the two co-resident blocks on a CU pair
//    heavy+light (makespan 24 tiles -> ~17).
// ---------------------------------------------------------------------------
__global__ __launch_bounds__(256)
void k_attn(const u16* __restrict__ qh, const u16* __restrict__ kh, const u16* __restrict__ vh,
            const u16* __restrict__ er, u16* __restrict__ opre,
            void* __restrict__ out, const unsigned* __restrict__ flag)
{
    __shared__ __align__(16) u16 Vt[64][72];
    __shared__ float Rs[4][16][132];
    __shared__ __align__(16) u16 Ps[4][16][72];

    const int t    = threadIdx.x;
    const int lane = t & 63;
    const int w    = t >> 6;
    const int q4   = lane >> 4;
    const int l16  = lane & 15;
    const int bh   = blockIdx.x;
    const int by   = blockIdx.y;
    const int qt   = (by < 8) ? (15 - by) : (by - 8);   // complementary pairing
    const int r0   = qt * 64;
    const int isf32 = (*flag != 0u);
    const size_t obase = (size_t)bh * (SEQ * SEQ);

    // Zero-fill complements: qe[r][j]=0 for j<1023-r ; S_rel[r][c]=0 for c>r.
    for (int ml = w; ml < 64; ml += 4) {
        const int r  = r0 + ml;
        const int Lz = SEQ - 1 - r;
        const size_t rq = OUT_OFF_QE   + obase + (size_t)r * SEQ;
        const size_t rs = OUT_OFF_SREL + obase + (size_t)r * SEQ + r + 1;
        for (int c2 = lane; c2 < Lz; c2 += 64) {
            st_out(out, rq + c2, 0.f, isf32);
            st_out(out, rs + c2, 0.f, isf32);
        }
    }

    bf16x8 aQ[2];
    #pragma unroll
    for (int kc = 0; kc < 2; ++kc)
        aQ[kc] = *(const bf16x8*)(qh + ((size_t)bh * SEQ + r0 + w * 16 + l16) * HDIM + kc * 32 + q4 * 8);

    f32x4 Oacc[4] = {};
    float mi[4] = { -1e30f, -1e30f, -1e30f, -1e30f };
    float li[4] = {};

    for (int tt = 0; tt <= qt; ++tt) {
        const int c0 = tt * 64;
        const int jbase = 960 + c0 - r0;    // e_r row of band base; >= 0
        const int diag = (tt == qt);

        __syncthreads();
        // V transposed into LDS: Vt[d][c] (only V needs staging: transpose)
        #pragma unroll
        for (int i = 0; i < 4; ++i) {
            int idx = i * 256 + t;
            int c = idx >> 4, dg = (idx & 15) << 2;
            ushort4 v = *(const ushort4*)(vh + ((size_t)bh * SEQ + c0 + c) * HDIM + dg);
            Vt[dg + 0][c] = v.x; Vt[dg + 1][c] = v.y;
            Vt[dg + 2][c] = v.z; Vt[dg + 3][c] = v.w;
        }
        __syncthreads();

        // R[m][nn] = Q[r0+w*16+m] . E[jbase+nn]  (B-frags straight from global)
        {
            f32x4 Racc[8] = {};
            #pragma unroll
            for (int nt = 0; nt < 8; ++nt) {
                int j = jbase + nt * 16 + l16; if (j > 1023) j = 1023;
                const u16* ep = er + (size_t)j * HDIM + q4 * 8;
                Racc[nt] = MFMA16(aQ[0], *(const bf16x8*)(ep),      Racc[nt]);
                Racc[nt] = MFMA16(aQ[1], *(const bf16x8*)(ep + 32), Racc[nt]);
            }
            #pragma unroll
            for (int nt = 0; nt < 8; ++nt)
                #pragma unroll
                for (int reg = 0; reg < 4; ++reg)
                    Rs[w][q4 * 4 + reg][nt * 16 + l16] = Racc[nt][reg];

            // Fused band store to qe and S_rel.
            #pragma unroll
            for (int nt = 0; nt < 8; ++nt) {
                const int nn = nt * 16 + l16;
                #pragma unroll
                for (int reg = 0; reg < 4; ++reg) {
                    const int mloc = w * 16 + q4 * 4 + reg;
                    const int rel  = nn - 63 + mloc;
                    if (rel >= 0 && rel < 64 && (!diag || nn <= 63)) {
                        const int r = r0 + mloc;
                        const float v = Racc[nt][reg];
                        st_out(out, OUT_OFF_SREL + obase + (size_t)r * SEQ + (c0 + rel),   v, isf32);
                        st_out(out, OUT_OFF_QE   + obase + (size_t)r * SEQ + (jbase + nn), v, isf32);
                    }
                }
            }
        }

        // S = QK^T  (K B-frags straight from global, L2-hot)
        f32x4 Sacc[4] = {};
        #pragma unroll
        for (int nt = 0; nt < 4; ++nt) {
            const u16* kp = kh + ((size_t)bh * SEQ + c0 + nt * 16 + l16) * HDIM + q4 * 8;
            Sacc[nt] = MFMA16(aQ[0], *(const bf16x8*)(kp),      Sacc[nt]);
            Sacc[nt] = MFMA16(aQ[1], *(const bf16x8*)(kp + 32), Sacc[nt]);
        }

        // assemble + online softmax (per output row: q4*4+reg)
        #pragma unroll
        for (int reg = 0; reg < 4; ++reg) {
            const int m16  = q4 * 4 + reg;
            const int mloc = w * 16 + m16;
            float sv[4];
            #pragma unroll
            for (int nt = 0; nt < 4; ++nt) {
                const int nloc = nt * 16 + l16;
                const int jj = 63 + nloc - mloc;          // 0..126
                float s = Sacc[nt][reg] * 0.125f + Rs[w][m16][jj];
                if (diag && (nloc > mloc)) s = -1e30f;
                sv[nt] = s;
            }
            float mx = fmaxf(fmaxf(sv[0], sv[1]), fmaxf(sv[2], sv[3]));
            #pragma unroll
            for (int off = 1; off < 16; off <<= 1) mx = fmaxf(mx, __shfl_xor(mx, off));
            const float mnew = fmaxf(mi[reg], mx);
            const float al   = __expf(mi[reg] - mnew);
            mi[reg] = mnew;
            float psum = 0.f;
            #pragma unroll
            for (int nt = 0; nt < 4; ++nt) {
                const float p = __expf(sv[nt] - mnew);
                psum += p;
                Ps[w][m16][nt * 16 + l16] = f2b(p);
            }
            #pragma unroll
            for (int off = 1; off < 16; off <<= 1) psum += __shfl_xor(psum, off);
            li[reg] = li[reg] * al + psum;
            #pragma unroll
            for (int dt = 0; dt < 4; ++dt) Oacc[dt][reg] *= al;
        }

        // O += P V
        #pragma unroll
        for (int kc = 0; kc < 2; ++kc) {
            bf16x8 aP = *(const bf16x8*)&Ps[w][l16][kc * 32 + q4 * 8];
            #pragma unroll
            for (int dt = 0; dt < 4; ++dt) {
                bf16x8 bV = *(const bf16x8*)&Vt[dt * 16 + l16][kc * 32 + q4 * 8];
                Oacc[dt] = MFMA16(aP, bV, Oacc[dt]);
            }
        }
    }

    const int b = bh >> 4, h = bh & 15;
    #pragma unroll
    for (int dt = 0; dt < 4; ++dt) {
        #pragma unroll
        for (int reg = 0; reg < 4; ++reg) {
            const int r = r0 + w * 16 + q4 * 4 + reg;
            const int d = dt * 16 + l16;
            opre[((size_t)b * SEQ + r) * DMODEL + h * HDIM + d] = f2b(Oacc[dt][reg] / li[reg]);
        }
    }
}

// ---------------------------------------------------------------------------
extern "C" void kernel_launch(void* const* d_in, const int* in_sizes, int n_in,
                              void* d_out, int out_size, void* d_ws, size_t ws_size,
                              hipStream_t stream)
{
    u16* ws16 = (u16*)d_ws;
    unsigned* flag = (unsigned*)d_ws;
    u16* cq   = ws16 + 8;
    u16* ck   = cq   + 2097152;
    u16* cv   = ck   + 2097152;
    u16* cwqT = cv   + 2097152;
    u16* cwkT = cwqT + 1048576;
    u16* cwvT = cwkT + 1048576;
    u16* cwoT = cwvT + 1048576;
    u16* cbq  = cwoT + 1048576;
    u16* cbk  = cbq  + 1024;
    u16* cbv  = cbk  + 1024;
    u16* cbo  = cbv  + 1024;
    u16* cer  = cbo  + 1024;
    u16* qh   = cer  + 65536;
    u16* kh   = qh   + 2097152;
    u16* vh   = kh   + 2097152;
    u16* opre = vh   + 2097152;

    dim3 blk(256);

    k_detect<<<1, blk, 0, stream>>>((const u16*)d_in[0], flag);

    k_conv_all<<<dim3(7236), blk, 0, stream>>>(d_in[0], d_in[1], d_in[2],
                                               d_in[4], d_in[6], d_in[8], d_in[10],
                                               d_in[5], d_in[7], d_in[9], d_in[11], d_in[12],
                                               cq, ck, cv, cwqT, cwkT, cwvT, cwoT,
                                               cbq, cbk, cbv, cbo, cer, flag);

    k_gemm<<<dim3(8, 16, 3), blk, 0, stream>>>(cq, ck, cv, cwqT, cwkT, cwvT,
                                               cbq, cbk, cbv, qh, kh, vh,
                                               nullptr, flag, 0);
    k_attn<<<dim3(32, 16), blk, 0, stream>>>(qh, kh, vh, cer, opre, d_out, flag);
    k_gemm<<<dim3(8, 16, 1), blk, 0, stream>>>(opre, opre, opre, cwoT, cwoT, cwoT,
                                               cbo, cbo, cbo, nullptr, nullptr, nullptr,
                                               d_out, flag, 1);
}

// Round 2
// 479.740 us; speedup vs baseline: 1.0516x; 1.0516x over previous
//
#include <hip/hip_runtime.h>
#include <hip/hip_bf16.h>

typedef unsigned short u16;
typedef __attribute__((ext_vector_type(8))) short    bf16x8;  // MFMA A/B frag (8 bf16)
typedef __attribute__((ext_vector_type(8))) unsigned short u16x8;
typedef __attribute__((ext_vector_type(4))) float    f32x4;   // MFMA C/D frag

typedef __attribute__((address_space(1))) void gvoid;
typedef __attribute__((address_space(3))) void lvoid;

#define SEQ    1024
#define DMODEL 1024
#define NHEAD  16
#define HDIM   64

#define OUT_OFF_SREL 2097152UL
#define OUT_OFF_QE   35651584UL

#define MFMA16(a, b, c) __builtin_amdgcn_mfma_f32_16x16x32_bf16((a), (b), (c), 0, 0, 0)

__device__ __forceinline__ float b2f(u16 u) {
    union { unsigned int i; float f; } x; x.i = ((unsigned int)u) << 16; return x.f;
}
__device__ __forceinline__ u16 f2b(float f) {
    union { __hip_bfloat16 h; u16 u; } x; x.h = __float2bfloat16(f); return x.u;
}
__device__ __forceinline__ void st_out(void* p, size_t idx, float v, int isf32) {
    if (isf32) ((float*)p)[idx] = v;
    else       ((u16*)p)[idx]   = f2b(v);
}
// async global->LDS, 16B per lane. LDS dest = wave-uniform base + lane*16.
__device__ __forceinline__ void gload_lds16(const u16* g, u16* l) {
    __builtin_amdgcn_global_load_lds((gvoid*)g, (lvoid*)l, 16, 0, 0);
}

// ---------------------------------------------------------------------------
// dtype detect (fp32 vs bf16)
// ---------------------------------------------------------------------------
__global__ __launch_bounds__(256)
void k_detect(const u16* __restrict__ q, unsigned* __restrict__ flag)
{
    __shared__ int cnt;
    if (threadIdx.x == 0) cnt = 0;
    __syncthreads();
    int plaus = 0;
    for (int i = threadIdx.x; i < 4096; i += 256) {
        u16 u = q[2 * i];
        int e = (u >> 7) & 0xFF;
        if (e >= 102 && e <= 130) plaus++;
    }
    atomicAdd(&cnt, plaus);
    __syncthreads();
    if (threadIdx.x == 0) *flag = (cnt < 2048) ? 1u : 0u;
}

// ---------------------------------------------------------------------------
// ALL conversions in one launch:
//   blocks [0,6144):    q/k/v convert (2048 blocks each)
//   blocks [6144,7168): 4x 1024x1024 transpose+convert (256 blocks each)
//   blocks [7168,7236): e_r (64 blocks) + 4 biases
// ---------------------------------------------------------------------------
__global__ __launch_bounds__(256)
void k_conv_all(const void* __restrict__ sq, const void* __restrict__ sk, const void* __restrict__ sv,
                const void* __restrict__ w0, const void* __restrict__ w1,
                const void* __restrict__ w2, const void* __restrict__ w3,
                const void* __restrict__ b0, const void* __restrict__ b1,
                const void* __restrict__ b2, const void* __restrict__ b3,
                const void* __restrict__ erp,
                u16* __restrict__ cq, u16* __restrict__ ck, u16* __restrict__ cv,
                u16* __restrict__ d0, u16* __restrict__ d1,
                u16* __restrict__ d2, u16* __restrict__ d3,
                u16* __restrict__ db0, u16* __restrict__ db1,
                u16* __restrict__ db2, u16* __restrict__ db3,
                u16* __restrict__ der, const unsigned* __restrict__ flag)
{
    __shared__ u16 tile[64][65];
    const int t = threadIdx.x;
    const int b = blockIdx.x;
    const int isf32 = (*flag != 0u);

    if (b < 6144) {                      // q/k/v: 2048 blocks per tensor, exact
        const int z = b >> 11;
        const void* src = (z == 0) ? sq : (z == 1) ? sk : sv;
        u16* dst = (z == 0) ? cq : (z == 1) ? ck : cv;
        const int i = (b & 2047) * 256 + t;
        if (isf32) {
            float4 f = ((const float4*)src)[i];
            ushort4 o;
            o.x = f2b(f.x); o.y = f2b(f.y); o.z = f2b(f.z); o.w = f2b(f.w);
            ((ushort4*)dst)[i] = o;
        } else {
            ((ushort4*)dst)[i] = ((const ushort4*)src)[i];
        }
    } else if (b < 7168) {               // weight transpose
        const int bb = b - 6144;
        const int z  = bb >> 8;
        const void* src = (z == 0) ? w0 : (z == 1) ? w1 : (z == 2) ? w2 : w3;
        u16* dst = (z == 0) ? d0 : (z == 1) ? d1 : (z == 2) ? d2 : d3;
        const int n0 = (bb & 15) * 64;
        const int k0 = ((bb >> 4) & 15) * 64;

        #pragma unroll
        for (int i = 0; i < 4; ++i) {
            int idx = i * 256 + t;
            int r  = idx >> 4;
            int cg = (idx & 15) << 2;
            if (isf32) {
                float4 f = *(const float4*)((const float*)src + (size_t)(k0 + r) * 1024 + n0 + cg);
                tile[cg + 0][r] = f2b(f.x); tile[cg + 1][r] = f2b(f.y);
                tile[cg + 2][r] = f2b(f.z); tile[cg + 3][r] = f2b(f.w);
            } else {
                ushort4 u = *(const ushort4*)((const u16*)src + (size_t)(k0 + r) * 1024 + n0 + cg);
                tile[cg + 0][r] = u.x; tile[cg + 1][r] = u.y;
                tile[cg + 2][r] = u.z; tile[cg + 3][r] = u.w;
            }
        }
        __syncthreads();
        #pragma unroll
        for (int i = 0; i < 4; ++i) {
            int idx = i * 256 + t;
            int nl = idx >> 4;
            int kg = (idx & 15) << 2;
            ushort4 o;
            o.x = tile[nl][kg + 0]; o.y = tile[nl][kg + 1];
            o.z = tile[nl][kg + 2]; o.w = tile[nl][kg + 3];
            *(ushort4*)(dst + (size_t)(n0 + nl) * 1024 + k0 + kg) = o;
        }
    } else {                             // e_r + biases
        const int bx = b - 7168;
        const void* src; u16* dst; int i;
        if (bx < 64) { src = erp; dst = der; i = bx * 256 + t; }
        else {
            const int which = bx - 64;
            src = (which == 0) ? b0 : (which == 1) ? b1 : (which == 2) ? b2 : b3;
            dst = (which == 0) ? db0 : (which == 1) ? db1 : (which == 2) ? db2 : db3;
            i = t;
        }
        if (isf32) {
            float4 f = ((const float4*)src)[i];
            ushort4 o;
            o.x = f2b(f.x); o.y = f2b(f.y); o.z = f2b(f.z); o.w = f2b(f.w);
            ((ushort4*)dst)[i] = o;
        } else {
            ((ushort4*)dst)[i] = ((const ushort4*)src)[i];
        }
    }
}

// ---------------------------------------------------------------------------
// MFMA GEMM (m97 structure): global_load_lds width-16 staging, linear LDS.
// C[m][n] = sum_k A[m][k] * Wt[n][k]. 128x128 tile, BK=64.
// ---------------------------------------------------------------------------
__global__ __launch_bounds__(256)
void k_gemm(const u16* __restrict__ Aq, const u16* __restrict__ Ak, const u16* __restrict__ Av,
            const u16* __restrict__ Wtq, const u16* __restrict__ Wtk, const u16* __restrict__ Wtv,
            const u16* __restrict__ Bq, const u16* __restrict__ Bk, const u16* __restrict__ Bv,
            u16* __restrict__ Oq, u16* __restrict__ Ok, u16* __restrict__ Ov,
            void* __restrict__ out_flat, const unsigned* __restrict__ flag, int mode)
{
    __shared__ __align__(16) u16 Xs[128][64];   // linear: global_load_lds dest
    __shared__ __align__(16) u16 Ws[128][64];

    const int z = blockIdx.z;
    const u16* A  = (z == 0) ? Aq : (z == 1) ? Ak : Av;
    const u16* Wt = (z == 0) ? Wtq : (z == 1) ? Wtk : Wtv;
    const u16* Bi = (z == 0) ? Bq : (z == 1) ? Bk : Bv;
    u16* O = (z == 0) ? Oq : (z == 1) ? Ok : Ov;

    const int t    = threadIdx.x;
    const int lane = t & 63;
    const int w    = t >> 6;
    const int q4   = lane >> 4;
    const int l16  = lane & 15;
    const int wy   = w >> 1, wx = w & 1;
    const int m0   = blockIdx.y * 128;
    const int n0   = blockIdx.x * 128;

    f32x4 acc[4][4] = {};

    for (int k0 = 0; k0 < DMODEL; k0 += 64) {
        __syncthreads();
        #pragma unroll
        for (int i = 0; i < 4; ++i) {
            const int idx = i * 256 + t;
            const int row = idx >> 3;
            const int kg  = (idx & 7) << 3;
            const int wb  = i * 256 + (t & 192);            // wave-uniform LDS base (16B units)
            gload_lds16(A  + (size_t)(m0 + row) * 1024 + k0 + kg, (u16*)Xs + (size_t)wb * 8);
            gload_lds16(Wt + (size_t)(n0 + row) * 1024 + k0 + kg, (u16*)Ws + (size_t)wb * 8);
        }
        __syncthreads();                                    // drains vmcnt (m97 pattern)
        #pragma unroll
        for (int kc = 0; kc < 2; ++kc) {
            bf16x8 af[4], bfr[4];
            #pragma unroll
            for (int mt = 0; mt < 4; ++mt)
                af[mt] = *(const bf16x8*)&Xs[wy * 64 + mt * 16 + l16][kc * 32 + q4 * 8];
            #pragma unroll
            for (int nt = 0; nt < 4; ++nt)
                bfr[nt] = *(const bf16x8*)&Ws[wx * 64 + nt * 16 + l16][kc * 32 + q4 * 8];
            #pragma unroll
            for (int mt = 0; mt < 4; ++mt)
                #pragma unroll
                for (int nt = 0; nt < 4; ++nt)
                    acc[mt][nt] = MFMA16(af[mt], bfr[nt], acc[mt][nt]);
        }
    }

    const int isf32 = (*flag != 0u);
    float bias[4];
    #pragma unroll
    for (int nt = 0; nt < 4; ++nt) bias[nt] = b2f(Bi[n0 + wx * 64 + nt * 16 + l16]);

    #pragma unroll
    for (int mt = 0; mt < 4; ++mt) {
        #pragma unroll
        for (int nt = 0; nt < 4; ++nt) {
            #pragma unroll
            for (int reg = 0; reg < 4; ++reg) {
                const int m = m0 + wy * 64 + mt * 16 + q4 * 4 + reg;
                const int n = n0 + wx * 64 + nt * 16 + l16;
                const float v = acc[mt][nt][reg] + bias[nt];
                if (mode == 0) {
                    const int b = m >> 10, s = m & 1023, h = n >> 6, d = n & 63;
                    O[(((size_t)(b * NHEAD + h)) * SEQ + s) * HDIM + d] = f2b(v);
                } else {
                    st_out(out_flat, (size_t)m * DMODEL + n, v, isf32);
                }
            }
        }
    }
}

// ---------------------------------------------------------------------------
// k_attn (MFMA flash, FUSED qe/S_rel producer) — round-0 known-good version.
// Per block (bh, 64-row q-tile). Wave w -> score rows 16w..16w+15.
// Per c-tile: R = Q.E band (stored to BOTH qe and S_rel outputs),
//             S = QK^T*0.125 + R(banded), online softmax, O += P V.
// Zero complements of both outputs are filled by the same block (its rows).
// ---------------------------------------------------------------------------
__global__ __launch_bounds__(256)
void k_attn(const u16* __restrict__ qh, const u16* __restrict__ kh, const u16* __restrict__ vh,
            const u16* __restrict__ er, u16* __restrict__ opre,
            void* __restrict__ out, const unsigned* __restrict__ flag)
{
    __shared__ __align__(16) u16 Ks[64][72];
    __shared__ __align__(16) u16 Vt[64][72];
    __shared__ __align__(16) u16 Es[128][72];
    __shared__ float Rs[4][16][130];
    __shared__ __align__(16) u16 Ps[4][16][72];

    const int t    = threadIdx.x;
    const int lane = t & 63;
    const int w    = t >> 6;
    const int q4   = lane >> 4;
    const int l16  = lane & 15;
    const int bh   = blockIdx.x;
    const int qt   = 15 - blockIdx.y;       // heavy q-tiles dispatched first
    const int r0   = qt * 64;
    const int isf32 = (*flag != 0u);
    const size_t obase = (size_t)bh * (SEQ * SEQ);

    // Zero-fill the complements for this block's rows:
    //   qe[r][j]=0 for j<1023-r ; S_rel[r][c]=0 for c>r.
    for (int ml = w; ml < 64; ml += 4) {
        const int r  = r0 + ml;
        const int Lz = SEQ - 1 - r;
        const size_t rq = OUT_OFF_QE   + obase + (size_t)r * SEQ;
        const size_t rs = OUT_OFF_SREL + obase + (size_t)r * SEQ + r + 1;
        for (int c2 = lane; c2 < Lz; c2 += 64) {
            st_out(out, rq + c2, 0.f, isf32);
            st_out(out, rs + c2, 0.f, isf32);
        }
    }

    bf16x8 aQ[2];
    #pragma unroll
    for (int kc = 0; kc < 2; ++kc)
        aQ[kc] = *(const bf16x8*)(qh + ((size_t)bh * SEQ + r0 + w * 16 + l16) * HDIM + kc * 32 + q4 * 8);

    f32x4 Oacc[4] = {};
    float mi[4] = { -1e30f, -1e30f, -1e30f, -1e30f };
    float li[4] = {};

    for (int tt = 0; tt <= qt; ++tt) {
        const int c0 = tt * 64;
        const int jbase = 960 + c0 - r0;    // e_r row of Es[0]; >= 0
        const int diag = (tt == qt);

        __syncthreads();
        // K rows: 64x64 u16 = 2 iters x 256 thr x 8
        #pragma unroll
        for (int i = 0; i < 2; ++i) {
            int idx = i * 256 + t;
            int row = idx >> 3, kg = (idx & 7) << 3;
            *(u16x8*)&Ks[row][kg] = *(const u16x8*)(kh + ((size_t)bh * SEQ + c0 + row) * HDIM + kg);
        }
        // V transposed: Vt[d][c]
        #pragma unroll
        for (int i = 0; i < 4; ++i) {
            int idx = i * 256 + t;
            int c = idx >> 4, dg = (idx & 15) << 2;
            ushort4 v = *(const ushort4*)(vh + ((size_t)bh * SEQ + c0 + c) * HDIM + dg);
            Vt[dg + 0][c] = v.x; Vt[dg + 1][c] = v.y;
            Vt[dg + 2][c] = v.z; Vt[dg + 3][c] = v.w;
        }
        // E rows jbase..jbase+127: 4 iters x 256 x 8 (clamped rows only reach
        // masked/invalid lanes)
        #pragma unroll
        for (int i = 0; i < 4; ++i) {
            int idx = i * 256 + t;
            int row = idx >> 3, kg = (idx & 7) << 3;
            int j = jbase + row; if (j > 1023) j = 1023;
            *(u16x8*)&Es[row][kg] = *(const u16x8*)(er + (size_t)j * HDIM + kg);
        }
        __syncthreads();

        // R[m][nn] = Q[r0+w*16+m] . E[jbase+nn]  (16 rows x 128 nn per wave)
        {
            f32x4 Racc[8] = {};
            #pragma unroll
            for (int kc = 0; kc < 2; ++kc) {
                #pragma unroll
                for (int nt = 0; nt < 8; ++nt) {
                    bf16x8 bfr = *(const bf16x8*)&Es[nt * 16 + l16][kc * 32 + q4 * 8];
                    Racc[nt] = MFMA16(aQ[kc], bfr, Racc[nt]);
                }
            }
            #pragma unroll
            for (int nt = 0; nt < 8; ++nt)
                #pragma unroll
                for (int reg = 0; reg < 4; ++reg)
                    Rs[w][q4 * 4 + reg][nt * 16 + l16] = Racc[nt][reg];

            // Fused band store: value at (row r, col c=c0+rel) of S_rel and
            // (row r, col j=jbase+nn) of qe, where rel = nn-63+mloc.
            #pragma unroll
            for (int nt = 0; nt < 8; ++nt) {
                const int nn = nt * 16 + l16;
                #pragma unroll
                for (int reg = 0; reg < 4; ++reg) {
                    const int mloc = w * 16 + q4 * 4 + reg;
                    const int rel  = nn - 63 + mloc;
                    if (rel >= 0 && rel < 64 && (!diag || nn <= 63)) {
                        const int r = r0 + mloc;
                        const float v = Racc[nt][reg];
                        st_out(out, OUT_OFF_SREL + obase + (size_t)r * SEQ + (c0 + rel),   v, isf32);
                        st_out(out, OUT_OFF_QE   + obase + (size_t)r * SEQ + (jbase + nn), v, isf32);
                    }
                }
            }
        }

        // S = QK^T
        f32x4 Sacc[4] = {};
        #pragma unroll
        for (int kc = 0; kc < 2; ++kc) {
            #pragma unroll
            for (int nt = 0; nt < 4; ++nt) {
                bf16x8 bfr = *(const bf16x8*)&Ks[nt * 16 + l16][kc * 32 + q4 * 8];
                Sacc[nt] = MFMA16(aQ[kc], bfr, Sacc[nt]);
            }
        }

        // assemble + online softmax (per output row: q4*4+reg)
        #pragma unroll
        for (int reg = 0; reg < 4; ++reg) {
            const int m16  = q4 * 4 + reg;
            const int mloc = w * 16 + m16;
            float sv[4];
            #pragma unroll
            for (int nt = 0; nt < 4; ++nt) {
                const int nloc = nt * 16 + l16;
                const int jj = 63 + nloc - mloc;          // 0..126
                float s = Sacc[nt][reg] * 0.125f + Rs[w][m16][jj];
                if (diag && (nloc > mloc)) s = -1e30f;
                sv[nt] = s;
            }
            float mx = fmaxf(fmaxf(sv[0], sv[1]), fmaxf(sv[2], sv[3]));
            #pragma unroll
            for (int off = 1; off < 16; off <<= 1) mx = fmaxf(mx, __shfl_xor(mx, off));
            const float mnew = fmaxf(mi[reg], mx);
            const float al   = __expf(mi[reg] - mnew);
            mi[reg] = mnew;
            float psum = 0.f;
            #pragma unroll
            for (int nt = 0; nt < 4; ++nt) {
                const float p = __expf(sv[nt] - mnew);
                psum += p;
                Ps[w][m16][nt * 16 + l16] = f2b(p);
            }
            #pragma unroll
            for (int off = 1; off < 16; off <<= 1) psum += __shfl_xor(psum, off);
            li[reg] = li[reg] * al + psum;
            #pragma unroll
            for (int dt = 0; dt < 4; ++dt) Oacc[dt][reg] *= al;
        }

        // O += P V
        #pragma unroll
        for (int kc = 0; kc < 2; ++kc) {
            bf16x8 aP = *(const bf16x8*)&Ps[w][l16][kc * 32 + q4 * 8];
            #pragma unroll
            for (int dt = 0; dt < 4; ++dt) {
                bf16x8 bV = *(const bf16x8*)&Vt[dt * 16 + l16][kc * 32 + q4 * 8];
                Oacc[dt] = MFMA16(aP, bV, Oacc[dt]);
            }
        }
    }

    const int b = bh >> 4, h = bh & 15;
    #pragma unroll
    for (int dt = 0; dt < 4; ++dt) {
        #pragma unroll
        for (int reg = 0; reg < 4; ++reg) {
            const int r = r0 + w * 16 + q4 * 4 + reg;
            const int d = dt * 16 + l16;
            opre[((size_t)b * SEQ + r) * DMODEL + h * HDIM + d] = f2b(Oacc[dt][reg] / li[reg]);
        }
    }
}

// ---------------------------------------------------------------------------
extern "C" void kernel_launch(void* const* d_in, const int* in_sizes, int n_in,
                              void* d_out, int out_size, void* d_ws, size_t ws_size,
                              hipStream_t stream)
{
    u16* ws16 = (u16*)d_ws;
    unsigned* flag = (unsigned*)d_ws;
    u16* cq   = ws16 + 8;
    u16* ck   = cq   + 2097152;
    u16* cv   = ck   + 2097152;
    u16* cwqT = cv   + 2097152;
    u16* cwkT = cwqT + 1048576;
    u16* cwvT = cwkT + 1048576;
    u16* cwoT = cwvT + 1048576;
    u16* cbq  = cwoT + 1048576;
    u16* cbk  = cbq  + 1024;
    u16* cbv  = cbk  + 1024;
    u16* cbo  = cbv  + 1024;
    u16* cer  = cbo  + 1024;
    u16* qh   = cer  + 65536;
    u16* kh   = qh   + 2097152;
    u16* vh   = kh   + 2097152;
    u16* opre = vh   + 2097152;

    dim3 blk(256);

    k_detect<<<1, blk, 0, stream>>>((const u16*)d_in[0], flag);

    k_conv_all<<<dim3(7236), blk, 0, stream>>>(d_in[0], d_in[1], d_in[2],
                                               d_in[4], d_in[6], d_in[8], d_in[10],
                                               d_in[5], d_in[7], d_in[9], d_in[11], d_in[12],
                                               cq, ck, cv, cwqT, cwkT, cwvT, cwoT,
                                               cbq, cbk, cbv, cbo, cer, flag);

    k_gemm<<<dim3(8, 16, 3), blk, 0, stream>>>(cq, ck, cv, cwqT, cwkT, cwvT,
                                               cbq, cbk, cbv, qh, kh, vh,
                                               nullptr, flag, 0);
    k_attn<<<dim3(32, 16), blk, 0, stream>>>(qh, kh, vh, cer, opre, d_out, flag);
    k_gemm<<<dim3(8, 16, 1), blk, 0, stream>>>(opre, opre, opre, cwoT, cwoT, cwoT,
                                               cbo, cbo, cbo, nullptr, nullptr, nullptr,
                                               d_out, flag, 1);
}